// Round 6
// baseline (150.107 us; speedup 1.0000x reference)
//
#include <hip/hip_runtime.h>
#include <hip/hip_fp16.h>

#define HID 2048
#define FIVEH 10240
#define INP 128
#define BATCH 2048

// padded f32 LDS: phys(i) = i + (i>>4).  2048 -> 2176 float2 per buffer.
#define NPAD 2176

typedef _Float16 half8 __attribute__((ext_vector_type(8)));
typedef float f32x4 __attribute__((ext_vector_type(4)));

// load 8 consecutive f32, convert to half8 in-register
__device__ __forceinline__ half8 cvt8(const float* p) {
  float4 a = *(const float4*)p;
  float4 b = *(const float4*)(p + 4);
  half8 h;
  h[0] = (_Float16)a.x; h[1] = (_Float16)a.y; h[2] = (_Float16)a.z; h[3] = (_Float16)a.w;
  h[4] = (_Float16)b.x; h[5] = (_Float16)b.y; h[6] = (_Float16)b.z; h[7] = (_Float16)b.w;
  return h;
}

// ---------------- GEMM v3 (unchanged, verified): LDS-staged W, transposed epilogue ----
#define WSTRIDE 136
__global__ __launch_bounds__(256) void gemm_up(const float* __restrict__ A,
                                               const float* __restrict__ W,
                                               const float* __restrict__ bias,
                                               _Float16* __restrict__ up16,
                                               int row0, int nrows) {
  __shared__ _Float16 Ws[128 * WSTRIDE];
  int tid = threadIdx.x, wave = tid >> 6, lane = tid & 63;
  int bx = blockIdx.x;
  int by = blockIdx.y;
  int nl = lane & 15, quad = lane >> 4;

  {
    const float* src = W + (size_t)(bx * 128) * INP;
#pragma unroll
    for (int it = 0; it < 8; ++it) {
      int n = (it * 256 + tid) * 8;
      int col = n >> 7, k = n & 127;
      *(half8*)(Ws + col * WSTRIDE + k) = cvt8(src + n);
    }
  }

  half8 af[2][4];
  int rowbase = row0 + by * 128 + wave * 32;
#pragma unroll
  for (int mt = 0; mt < 2; ++mt) {
    const float* ar = A + (size_t)(rowbase + mt * 16 + nl) * INP + quad * 8;
#pragma unroll
    for (int ks = 0; ks < 4; ++ks) af[mt][ks] = cvt8(ar + ks * 32);
  }
  __syncthreads();

  f32x4 acc[2][8];
#pragma unroll
  for (int nt = 0; nt < 8; ++nt) {
    half8 bf[4];
#pragma unroll
    for (int ks = 0; ks < 4; ++ks)
      bf[ks] = *(const half8*)(Ws + (nt * 16 + nl) * WSTRIDE + quad * 8 + ks * 32);
#pragma unroll
    for (int mt = 0; mt < 2; ++mt) {
      f32x4 a = {0.f, 0.f, 0.f, 0.f};
#pragma unroll
      for (int ks = 0; ks < 4; ++ks)
        a = __builtin_amdgcn_mfma_f32_16x16x32_f16(af[mt][ks], bf[ks], a, 0, 0, 0);
      acc[mt][nt] = a;
    }
  }
  __syncthreads();

#pragma unroll
  for (int nt = 0; nt < 8; ++nt) {
    float bv = bias[bx * 128 + nt * 16 + nl];
#pragma unroll
    for (int mt = 0; mt < 2; ++mt) {
      int rl = wave * 32 + mt * 16 + quad * 4;
#pragma unroll
      for (int r = 0; r < 4; ++r)
        Ws[(rl + r) * WSTRIDE + nt * 16 + nl] = (_Float16)(acc[mt][nt][r] + bv);
    }
  }
  __syncthreads();

#pragma unroll
  for (int it = 0; it < 8; ++it) {
    int v = it * 256 + tid;
    int r = v >> 4, c8 = (v & 15) * 8;
    *(half8*)(up16 + (size_t)(by * 128 + r) * FIVEH + bx * 128 + c8) =
        *(const half8*)(Ws + r * WSTRIDE + c8);
  }
}

// ---------------- f32 complex helper ----------------
__device__ __forceinline__ float2 cmulcs(float2 a, float c, float s) {
  float2 r; r.x = a.x * c - a.y * s; r.y = a.x * s + a.y * c; return r;  // a*(c+is)
}

// ---------------- radix-8 Stockham FFT, padded f32 LDS (2048 = 8*8*8*4) ----------
// o_j = sum_m y_m e^{i*sgn*2pi*jm/8} (verified R4/R5).
__device__ __forceinline__ void dft8(const float2 y[8], float2 o[8], float sgn) {
  const float R2 = 0.70710678118654752f;
  float ta0r = y[0].x + y[4].x, ta0i = y[0].y + y[4].y;
  float ta1r = y[0].x - y[4].x, ta1i = y[0].y - y[4].y;
  float ta2r = y[2].x + y[6].x, ta2i = y[2].y + y[6].y;
  float ta3r = y[2].x - y[6].x, ta3i = y[2].y - y[6].y;
  float E0r = ta0r + ta2r, E0i = ta0i + ta2i;
  float E2r = ta0r - ta2r, E2i = ta0i - ta2i;
  float E1r = ta1r - sgn * ta3i, E1i = ta1i + sgn * ta3r;
  float E3r = ta1r + sgn * ta3i, E3i = ta1i - sgn * ta3r;
  float tb0r = y[1].x + y[5].x, tb0i = y[1].y + y[5].y;
  float tb1r = y[1].x - y[5].x, tb1i = y[1].y - y[5].y;
  float tb2r = y[3].x + y[7].x, tb2i = y[3].y + y[7].y;
  float tb3r = y[3].x - y[7].x, tb3i = y[3].y - y[7].y;
  float O0r = tb0r + tb2r, O0i = tb0i + tb2i;
  float O2r = tb0r - tb2r, O2i = tb0i - tb2i;
  float O1r = tb1r - sgn * tb3i, O1i = tb1i + sgn * tb3r;
  float O3r = tb1r + sgn * tb3i, O3i = tb1i - sgn * tb3r;
  float p1r = R2 * (O1r - sgn * O1i), p1i = R2 * (O1i + sgn * O1r);
  float p2r = -sgn * O2i,             p2i = sgn * O2r;
  float p3r = -R2 * (O3r + sgn * O3i), p3i = R2 * (sgn * O3r - O3i);
  o[0].x = E0r + O0r; o[0].y = E0i + O0i;
  o[4].x = E0r - O0r; o[4].y = E0i - O0i;
  o[1].x = E1r + p1r; o[1].y = E1i + p1i;
  o[5].x = E1r - p1r; o[5].y = E1i - p1i;
  o[2].x = E2r + p2r; o[2].y = E2i + p2i;
  o[6].x = E2r - p2r; o[6].y = E2i - p2i;
  o[3].x = E3r + p3r; o[3].y = E3i + p3i;
  o[7].x = E3r - p3r; o[7].y = E3i - p3i;
}

// HEAD = radix-8 pass, L=1 (unit twiddles); writes contiguous padded block.
__device__ __forceinline__ void fft8_head(const float2 v[8], float2* dst, int tid, float sgn) {
  float2 o[8];
  dft8(v, o, sgn);
  float2* base = dst + (tid << 3) + (tid >> 1);
#pragma unroll
  for (int j = 0; j < 8; ++j) base[j] = o[j];
}

// radix-8 Stockham pass, L in {8,64}, padded addressing (verified R5).
template <int L>
__device__ __forceinline__ void fft8_pass(const float2* __restrict__ src,
                                          float2* __restrict__ dst, int tid, float sgn) {
  const int k = tid & (L - 1);
  float s1, c1;
  __sincosf(sgn * (0.78539816339744831f / (float)L) * (float)k, &s1, &c1);  // pi/(4L)*k
  float c2 = c1 * c1 - s1 * s1,  s2 = 2.f * c1 * s1;
  float c3 = c2 * c1 - s2 * s1,  s3 = c2 * s1 + s2 * c1;
  float c4 = c2 * c2 - s2 * s2,  s4 = 2.f * c2 * s2;
  float c5 = c4 * c1 - s4 * s1,  s5 = c4 * s1 + s4 * c1;
  float c6 = c4 * c2 - s4 * s2,  s6 = c4 * s2 + s4 * c2;
  float c7 = c4 * c3 - s4 * s3,  s7 = c4 * s3 + s4 * c3;
  const int rb = tid + (tid >> 4);  // PHI(tid)
  float2 y[8];
  y[0] = src[rb];
  y[1] = cmulcs(src[rb + 272],  c1, s1);
  y[2] = cmulcs(src[rb + 544],  c2, s2);
  y[3] = cmulcs(src[rb + 816],  c3, s3);
  y[4] = cmulcs(src[rb + 1088], c4, s4);
  y[5] = cmulcs(src[rb + 1360], c5, s5);
  y[6] = cmulcs(src[rb + 1632], c6, s6);
  y[7] = cmulcs(src[rb + 1904], c7, s7);
  float2 o[8];
  dft8(y, o, sgn);
  const int base = ((tid - k) << 3) + k;
#pragma unroll
  for (int j = 0; j < 8; ++j) {
    int a = base + j * L;
    dst[a + (a >> 4)] = o[j];
  }
}

// TAIL: radix-4 pass L=512 straight into registers; h[e] = point (tid + 256e).
__device__ __forceinline__ void fft_tail_f(const float2* __restrict__ src, float2 h[8],
                                           int tid, float sgn) {
#pragma unroll
  for (int t = 0; t < 2; ++t) {
    int i = tid + (t << 8);
    float s1, c1;
    __sincosf(sgn * (1.5707963267948966f / 512.f) * (float)i, &s1, &c1);
    float c2 = c1 * c1 - s1 * s1, s2 = 2.f * c1 * s1;
    float c3 = c1 * c2 - s1 * s2, s3 = c1 * s2 + s1 * c2;
    const int rb = i + (i >> 4);  // PHI(i)
    float2 x0 = src[rb], x1 = src[rb + 544], x2 = src[rb + 1088], x3 = src[rb + 1632];
    float y1r = x1.x * c1 - x1.y * s1, y1i = x1.x * s1 + x1.y * c1;
    float y2r = x2.x * c2 - x2.y * s2, y2i = x2.x * s2 + x2.y * c2;
    float y3r = x3.x * c3 - x3.y * s3, y3i = x3.x * s3 + x3.y * c3;
    float t0r = x0.x + y2r, t0i = x0.y + y2i;
    float t1r = x0.x - y2r, t1i = x0.y - y2i;
    float t2r = y1r + y3r, t2i = y1i + y3i;
    float t3r = y1r - y3r, t3i = y1i - y3i;
    h[t].x     = t0r + t2r;       h[t].y     = t0i + t2i;
    h[t + 4].x = t0r - t2r;       h[t + 4].y = t0i - t2i;
    h[t + 2].x = t1r - sgn * t3i; h[t + 2].y = t1i + sgn * t3r;
    h[t + 6].x = t1r + sgn * t3i; h[t + 6].y = t1i - sgn * t3r;
  }
}

// wave shfl reduce + tiny LDS combine (private red buffer per call site).
__device__ __forceinline__ void block_reduce2(float& pr, float& pi,
                                              float* redr, float* redi, int tid) {
  for (int off = 32; off > 0; off >>= 1) {
    pr += __shfl_down(pr, off, 64);
    pi += __shfl_down(pi, off, 64);
  }
  if ((tid & 63) == 0) { redr[tid >> 6] = pr; redi[tid >> 6] = pi; }
  __syncthreads();
  pr = redr[0] + redr[1] + redr[2] + redr[3];
  pi = redi[0] + redi[1] + redi[2] + redi[3];
}

// ---------------- the full row pipeline, ALL global inputs pre-loaded ----------------
// upv[s*8+e] = up value for phase s, element (tid+256e). hxr8/hxi8/pk/bt likewise.
// No global loads occur inside: every __syncthreads() is a memory fence, so loads
// placed per-phase (R2-R5) could not be hoisted and each phase paid a serial
// HBM/L2 latency wall. Prefetching collapses 6-7 serial walls into one.
__device__ __forceinline__ void row_pipeline(const float* upv,
                                             const float* hxr8, const float* hxi8,
                                             const int* pk, const float* bt,
                                             float2* sA, float2* sB,
                                             float* redr, float* redi,
                                             int tid, long b, float* out,
                                             long out_size_l, int omode) {
  float2 hreg[8];
  {
    float2 v[8];
#pragma unroll
    for (int e = 0; e < 8; ++e) {
      float sv, cv; __sincosf(upv[e], &sv, &cv);
      v[e].x = cv * hxr8[e] - sv * hxi8[e];
      v[e].y = cv * hxi8[e] + sv * hxr8[e];
    }
    fft8_head(v, sA, tid, -1.f);
  }
  __syncthreads();
  fft8_pass<8>(sA, sB, tid, -1.f);  __syncthreads();
  fft8_pass<64>(sB, sA, tid, -1.f); __syncthreads();
  fft_tail_f(sA, hreg, tid, -1.f);
  float cc[8], ss[8];
  {
    float pr = 0.f, pi = 0.f;
#pragma unroll
    for (int e = 0; e < 8; ++e) {
      float sv, cv; __sincosf(upv[24 + e], &sv, &cv);
      cc[e] = cv; ss[e] = sv;
      pr += cv * hreg[e].x + sv * hreg[e].y;
      pi += cv * hreg[e].y - sv * hreg[e].x;
    }
    block_reduce2(pr, pi, redr, redi, tid);
    const int wb = tid + (tid >> 4);  // PHI(tid); +272e per element
#pragma unroll
    for (int e = 0; e < 8; ++e) {
      sB[wb + 272 * e].x = hreg[e].x - 2.f * (cc[e] * pr - ss[e] * pi);
      sB[wb + 272 * e].y = hreg[e].y - 2.f * (cc[e] * pi + ss[e] * pr);
    }
  }
  __syncthreads();
  {
    const float invN = 1.0f / (float)HID;
    float2 v[8];
#pragma unroll
    for (int e = 0; e < 8; ++e) {
      float sv, cv; __sincosf(upv[8 + e], &sv, &cv);
      int p = pk[e];
      float2 hh = sB[p + (p >> 4)];
      v[e].x = (cv * hh.x - sv * hh.y) * invN;
      v[e].y = (cv * hh.y + sv * hh.x) * invN;
    }
    fft8_head(v, sA, tid, 1.f);
  }
  __syncthreads();
  fft8_pass<8>(sA, sB, tid, 1.f);  __syncthreads();
  fft8_pass<64>(sB, sA, tid, 1.f); __syncthreads();
  fft_tail_f(sA, hreg, tid, 1.f);
  float prj_r, prj_i;
  {
    float pr = 0.f, pi = 0.f;
#pragma unroll
    for (int e = 0; e < 8; ++e) {
      float sv, cv; __sincosf(upv[32 + e], &sv, &cv);
      cc[e] = cv; ss[e] = sv;
      pr += cv * hreg[e].x + sv * hreg[e].y;
      pi += cv * hreg[e].y - sv * hreg[e].x;
    }
    block_reduce2(pr, pi, redr + 4, redi + 4, tid);
    prj_r = pr; prj_i = pi;
  }
#pragma unroll
  for (int e = 0; e < 8; ++e) {
    int k = tid + (e << 8);
    float hr = hreg[e].x - 2.f * (cc[e] * prj_r - ss[e] * prj_i);
    float hi = hreg[e].y - 2.f * (cc[e] * prj_i + ss[e] * prj_r);
    float s3, c3; __sincosf(upv[16 + e], &s3, &c3);
    float zr = c3 * hr - s3 * hi;
    float zi = c3 * hi + s3 * hr;
    float mag = sqrtf(zr * zr + zi * zi);
    float nm = mag + bt[e];
    nm = nm > 0.f ? nm : 0.f;
    float orr, oii;
    if (mag > 0.f) { float sc = nm / mag; orr = zr * sc; oii = zi * sc; }
    else { orr = nm; oii = 0.f; }
    long m = b * HID + k;
    if (omode == 1) {
      const long half = (long)BATCH * HID;
      if (half + m < out_size_l) { out[m] = orr; out[half + m] = oii; }
    } else if (omode == 0) {
      if (2 * m + 1 < out_size_l) {
        float2 o; o.x = orr; o.y = oii;
        *(float2*)(out + 2 * m) = o;
      }
    } else {
      if (m < out_size_l) out[m] = orr;
    }
  }
}

// ---------------- row kernel: 1 row/block, padded f32 LDS, full prefetch ----------
// launch_bounds(256,4): 128-VGPR budget. Prefetched state 72 regs + pipeline peak
// ~35 fits; (256,8)'s 32-VGPR cap would spill (R1 lesson).
__global__ __launch_bounds__(256, 4) void urnn_row(const _Float16* __restrict__ up16,
                                                   const float* __restrict__ hxr,
                                                   const float* __restrict__ hxi,
                                                   const float* __restrict__ beta,
                                                   const int* __restrict__ perm,
                                                   float* __restrict__ out,
                                                   int row0, long out_size_l, int omode) {
  __shared__ float2 sA[NPAD], sB[NPAD];
  __shared__ float redr[8], redi[8];

  int tid = threadIdx.x;
  long b = row0 + blockIdx.x;
  const _Float16* uprow = up16 + (size_t)blockIdx.x * FIVEH;

  // ---- one-batch prefetch of everything this row reads (first-needed first) ----
  float upv[40], hxr8[8], hxi8[8], bt[8];
  int pk[8];
#pragma unroll
  for (int e = 0; e < 8; ++e) upv[e] = (float)uprow[tid + (e << 8)];
#pragma unroll
  for (int e = 0; e < 8; ++e) {
    int k = tid + (e << 8);
    hxr8[e] = hxr[(size_t)b * HID + k];
    hxi8[e] = hxi[(size_t)b * HID + k];
  }
#pragma unroll
  for (int s = 1; s < 5; ++s) {
#pragma unroll
    for (int e = 0; e < 8; ++e)
      upv[s * 8 + e] = (float)uprow[s * HID + tid + (e << 8)];
  }
#pragma unroll
  for (int e = 0; e < 8; ++e) pk[e] = perm[tid + (e << 8)];
#pragma unroll
  for (int e = 0; e < 8; ++e) bt[e] = beta[tid + (e << 8)];

  row_pipeline(upv, hxr8, hxi8, pk, bt, sA, sB, redr, redi,
               tid, b, out, out_size_l, omode);
}

// ---------------- ws-free fused fallback (f32-exact per-thread GEMM) ------------------
__global__ __launch_bounds__(256) void urnn_fused(const float* __restrict__ A,
                                                  const float* __restrict__ W,
                                                  const float* __restrict__ bias,
                                                  const float* __restrict__ hxr,
                                                  const float* __restrict__ hxi,
                                                  const float* __restrict__ beta,
                                                  const int* __restrict__ perm,
                                                  float* __restrict__ out,
                                                  long out_size_l, int omode) {
  __shared__ float2 sA[NPAD], sB[NPAD];
  __shared__ float redr[8], redi[8];
  __shared__ float4 xs4[INP / 4];

  int tid = threadIdx.x;
  long b = blockIdx.x;

  if (tid < INP / 4) xs4[tid] = ((const float4*)(A + (size_t)b * INP))[tid];
  __syncthreads();

  float upv[40];
#pragma unroll
  for (int se = 0; se < 40; ++se) {
    int n = ((se >> 3) << 11) + ((se & 7) << 8) + tid;
    upv[se] = bias[n];
  }
  for (int kb = 0; kb < 4; ++kb) {
    float4 xv[8];
#pragma unroll
    for (int j = 0; j < 8; ++j) xv[j] = xs4[kb * 8 + j];
#pragma unroll
    for (int se = 0; se < 40; ++se) {
      int n = ((se >> 3) << 11) + ((se & 7) << 8) + tid;
      const float4* wr = (const float4*)(W + (size_t)n * INP + (kb << 5));
      float a = 0.f;
#pragma unroll
      for (int j = 0; j < 8; ++j) {
        float4 wv = wr[j];
        a += xv[j].x * wv.x + xv[j].y * wv.y + xv[j].z * wv.z + xv[j].w * wv.w;
      }
      upv[se] += a;
    }
  }
  // upv layout is [s*8+e] (n = s*2048 + e*256 + tid), matching row_pipeline.

  float hxr8[8], hxi8[8], bt[8];
  int pk[8];
#pragma unroll
  for (int e = 0; e < 8; ++e) {
    int k = tid + (e << 8);
    hxr8[e] = hxr[(size_t)b * HID + k];
    hxi8[e] = hxi[(size_t)b * HID + k];
    pk[e] = perm[k];
    bt[e] = beta[k];
  }

  row_pipeline(upv, hxr8, hxi8, pk, bt, sA, sB, redr, redi,
               tid, b, out, out_size_l, omode);
}

extern "C" void kernel_launch(void* const* d_in, const int* in_sizes, int n_in,
                              void* d_out, int out_size, void* d_ws, size_t ws_size,
                              hipStream_t stream) {
  const float* input   = (const float*)d_in[0];
  const float* hx_real = (const float*)d_in[1];
  const float* hx_imag = (const float*)d_in[2];
  const float* W       = (const float*)d_in[3];
  const float* bvec    = (const float*)d_in[4];
  const float* beta    = (const float*)d_in[5];
  const int*   perm    = (const int*)d_in[6];

  int omode;
  if (out_size == BATCH * HID) omode = 2;
  else if (out_size == 2 * BATCH * HID) omode = 1;
  else omode = 0;

  const size_t rowbytes = (size_t)FIVEH * sizeof(_Float16);
  long chunk = (long)(ws_size / rowbytes);
  if (chunk > BATCH) chunk = BATCH;
  chunk &= ~127L;

  if (chunk >= 128) {
    _Float16* up16 = (_Float16*)d_ws;
    for (long row0 = 0; row0 < BATCH; row0 += chunk) {
      int rows = (int)((row0 + chunk <= BATCH) ? chunk : (BATCH - row0));
      dim3 g(FIVEH / 128, rows / 128);
      gemm_up<<<g, 256, 0, stream>>>(input, W, bvec, up16, (int)row0, rows);
      urnn_row<<<rows, 256, 0, stream>>>(up16, hx_real, hx_imag, beta, perm,
                                         (float*)d_out, (int)row0, (long)out_size, omode);
    }
  } else {
    urnn_fused<<<BATCH, 256, 0, stream>>>(input, W, bvec, hx_real, hx_imag, beta, perm,
                                          (float*)d_out, (long)out_size, omode);
  }
}

// Round 7
// 145.080 us; speedup vs baseline: 1.0347x; 1.0347x over previous
//
#include <hip/hip_runtime.h>
#include <hip/hip_fp16.h>

#define HID 2048
#define FIVEH 10240
#define INP 128
#define BATCH 2048

// padded f32 LDS: phys(i) = i + (i>>4).  2048 -> 2176 float2 per buffer.
#define NPAD 2176

typedef _Float16 half8 __attribute__((ext_vector_type(8)));
typedef float f32x4 __attribute__((ext_vector_type(4)));

// load 8 consecutive f32, convert to half8 in-register
__device__ __forceinline__ half8 cvt8(const float* p) {
  float4 a = *(const float4*)p;
  float4 b = *(const float4*)(p + 4);
  half8 h;
  h[0] = (_Float16)a.x; h[1] = (_Float16)a.y; h[2] = (_Float16)a.z; h[3] = (_Float16)a.w;
  h[4] = (_Float16)b.x; h[5] = (_Float16)b.y; h[6] = (_Float16)b.z; h[7] = (_Float16)b.w;
  return h;
}

// ---------------- GEMM v3 (unchanged, verified): LDS-staged W, transposed epilogue ----
#define WSTRIDE 136
__global__ __launch_bounds__(256) void gemm_up(const float* __restrict__ A,
                                               const float* __restrict__ W,
                                               const float* __restrict__ bias,
                                               _Float16* __restrict__ up16,
                                               int row0, int nrows) {
  __shared__ _Float16 Ws[128 * WSTRIDE];
  int tid = threadIdx.x, wave = tid >> 6, lane = tid & 63;
  int bx = blockIdx.x;
  int by = blockIdx.y;
  int nl = lane & 15, quad = lane >> 4;

  {
    const float* src = W + (size_t)(bx * 128) * INP;
#pragma unroll
    for (int it = 0; it < 8; ++it) {
      int n = (it * 256 + tid) * 8;
      int col = n >> 7, k = n & 127;
      *(half8*)(Ws + col * WSTRIDE + k) = cvt8(src + n);
    }
  }

  half8 af[2][4];
  int rowbase = row0 + by * 128 + wave * 32;
#pragma unroll
  for (int mt = 0; mt < 2; ++mt) {
    const float* ar = A + (size_t)(rowbase + mt * 16 + nl) * INP + quad * 8;
#pragma unroll
    for (int ks = 0; ks < 4; ++ks) af[mt][ks] = cvt8(ar + ks * 32);
  }
  __syncthreads();

  f32x4 acc[2][8];
#pragma unroll
  for (int nt = 0; nt < 8; ++nt) {
    half8 bf[4];
#pragma unroll
    for (int ks = 0; ks < 4; ++ks)
      bf[ks] = *(const half8*)(Ws + (nt * 16 + nl) * WSTRIDE + quad * 8 + ks * 32);
#pragma unroll
    for (int mt = 0; mt < 2; ++mt) {
      f32x4 a = {0.f, 0.f, 0.f, 0.f};
#pragma unroll
      for (int ks = 0; ks < 4; ++ks)
        a = __builtin_amdgcn_mfma_f32_16x16x32_f16(af[mt][ks], bf[ks], a, 0, 0, 0);
      acc[mt][nt] = a;
    }
  }
  __syncthreads();

#pragma unroll
  for (int nt = 0; nt < 8; ++nt) {
    float bv = bias[bx * 128 + nt * 16 + nl];
#pragma unroll
    for (int mt = 0; mt < 2; ++mt) {
      int rl = wave * 32 + mt * 16 + quad * 4;
#pragma unroll
      for (int r = 0; r < 4; ++r)
        Ws[(rl + r) * WSTRIDE + nt * 16 + nl] = (_Float16)(acc[mt][nt][r] + bv);
    }
  }
  __syncthreads();

#pragma unroll
  for (int it = 0; it < 8; ++it) {
    int v = it * 256 + tid;
    int r = v >> 4, c8 = (v & 15) * 8;
    *(half8*)(up16 + (size_t)(by * 128 + r) * FIVEH + bx * 128 + c8) =
        *(const half8*)(Ws + r * WSTRIDE + c8);
  }
}

// ---------------- f32 complex helper ----------------
__device__ __forceinline__ float2 cmulcs(float2 a, float c, float s) {
  float2 r; r.x = a.x * c - a.y * s; r.y = a.x * s + a.y * c; return r;  // a*(c+is)
}

// ---------------- radix-8 Stockham FFT, padded f32 LDS (2048 = 8*8*8*4) ----------
// o_j = sum_m y_m e^{i*sgn*2pi*jm/8} (verified R4/R5).
__device__ __forceinline__ void dft8(const float2 y[8], float2 o[8], float sgn) {
  const float R2 = 0.70710678118654752f;
  float ta0r = y[0].x + y[4].x, ta0i = y[0].y + y[4].y;
  float ta1r = y[0].x - y[4].x, ta1i = y[0].y - y[4].y;
  float ta2r = y[2].x + y[6].x, ta2i = y[2].y + y[6].y;
  float ta3r = y[2].x - y[6].x, ta3i = y[2].y - y[6].y;
  float E0r = ta0r + ta2r, E0i = ta0i + ta2i;
  float E2r = ta0r - ta2r, E2i = ta0i - ta2i;
  float E1r = ta1r - sgn * ta3i, E1i = ta1i + sgn * ta3r;
  float E3r = ta1r + sgn * ta3i, E3i = ta1i - sgn * ta3r;
  float tb0r = y[1].x + y[5].x, tb0i = y[1].y + y[5].y;
  float tb1r = y[1].x - y[5].x, tb1i = y[1].y - y[5].y;
  float tb2r = y[3].x + y[7].x, tb2i = y[3].y + y[7].y;
  float tb3r = y[3].x - y[7].x, tb3i = y[3].y - y[7].y;
  float O0r = tb0r + tb2r, O0i = tb0i + tb2i;
  float O2r = tb0r - tb2r, O2i = tb0i - tb2i;
  float O1r = tb1r - sgn * tb3i, O1i = tb1i + sgn * tb3r;
  float O3r = tb1r + sgn * tb3i, O3i = tb1i - sgn * tb3r;
  float p1r = R2 * (O1r - sgn * O1i), p1i = R2 * (O1i + sgn * O1r);
  float p2r = -sgn * O2i,             p2i = sgn * O2r;
  float p3r = -R2 * (O3r + sgn * O3i), p3i = R2 * (sgn * O3r - O3i);
  o[0].x = E0r + O0r; o[0].y = E0i + O0i;
  o[4].x = E0r - O0r; o[4].y = E0i - O0i;
  o[1].x = E1r + p1r; o[1].y = E1i + p1i;
  o[5].x = E1r - p1r; o[5].y = E1i - p1i;
  o[2].x = E2r + p2r; o[2].y = E2i + p2i;
  o[6].x = E2r - p2r; o[6].y = E2i - p2i;
  o[3].x = E3r + p3r; o[3].y = E3i + p3i;
  o[7].x = E3r - p3r; o[7].y = E3i - p3i;
}

// HEAD = radix-8 pass, L=1 (unit twiddles); writes contiguous padded block.
__device__ __forceinline__ void fft8_head(const float2 v[8], float2* dst, int tid, float sgn) {
  float2 o[8];
  dft8(v, o, sgn);
  float2* base = dst + (tid << 3) + (tid >> 1);
#pragma unroll
  for (int j = 0; j < 8; ++j) base[j] = o[j];
}

// radix-8 Stockham pass, L in {8,64}, padded addressing (verified R5).
template <int L>
__device__ __forceinline__ void fft8_pass(const float2* __restrict__ src,
                                          float2* __restrict__ dst, int tid, float sgn) {
  const int k = tid & (L - 1);
  float s1, c1;
  __sincosf(sgn * (0.78539816339744831f / (float)L) * (float)k, &s1, &c1);  // pi/(4L)*k
  float c2 = c1 * c1 - s1 * s1,  s2 = 2.f * c1 * s1;
  float c3 = c2 * c1 - s2 * s1,  s3 = c2 * s1 + s2 * c1;
  float c4 = c2 * c2 - s2 * s2,  s4 = 2.f * c2 * s2;
  float c5 = c4 * c1 - s4 * s1,  s5 = c4 * s1 + s4 * c1;
  float c6 = c4 * c2 - s4 * s2,  s6 = c4 * s2 + s4 * c2;
  float c7 = c4 * c3 - s4 * s3,  s7 = c4 * s3 + s4 * c3;
  const int rb = tid + (tid >> 4);  // PHI(tid)
  float2 y[8];
  y[0] = src[rb];
  y[1] = cmulcs(src[rb + 272],  c1, s1);
  y[2] = cmulcs(src[rb + 544],  c2, s2);
  y[3] = cmulcs(src[rb + 816],  c3, s3);
  y[4] = cmulcs(src[rb + 1088], c4, s4);
  y[5] = cmulcs(src[rb + 1360], c5, s5);
  y[6] = cmulcs(src[rb + 1632], c6, s6);
  y[7] = cmulcs(src[rb + 1904], c7, s7);
  float2 o[8];
  dft8(y, o, sgn);
  const int base = ((tid - k) << 3) + k;
#pragma unroll
  for (int j = 0; j < 8; ++j) {
    int a = base + j * L;
    dst[a + (a >> 4)] = o[j];
  }
}

// TAIL: radix-4 pass L=512 straight into registers; h[e] = point (tid + 256e).
__device__ __forceinline__ void fft_tail_f(const float2* __restrict__ src, float2 h[8],
                                           int tid, float sgn) {
#pragma unroll
  for (int t = 0; t < 2; ++t) {
    int i = tid + (t << 8);
    float s1, c1;
    __sincosf(sgn * (1.5707963267948966f / 512.f) * (float)i, &s1, &c1);
    float c2 = c1 * c1 - s1 * s1, s2 = 2.f * c1 * s1;
    float c3 = c1 * c2 - s1 * s2, s3 = c1 * s2 + s1 * c2;
    const int rb = i + (i >> 4);  // PHI(i)
    float2 x0 = src[rb], x1 = src[rb + 544], x2 = src[rb + 1088], x3 = src[rb + 1632];
    float y1r = x1.x * c1 - x1.y * s1, y1i = x1.x * s1 + x1.y * c1;
    float y2r = x2.x * c2 - x2.y * s2, y2i = x2.x * s2 + x2.y * c2;
    float y3r = x3.x * c3 - x3.y * s3, y3i = x3.x * s3 + x3.y * c3;
    float t0r = x0.x + y2r, t0i = x0.y + y2i;
    float t1r = x0.x - y2r, t1i = x0.y - y2i;
    float t2r = y1r + y3r, t2i = y1i + y3i;
    float t3r = y1r - y3r, t3i = y1i - y3i;
    h[t].x     = t0r + t2r;       h[t].y     = t0i + t2i;
    h[t + 4].x = t0r - t2r;       h[t + 4].y = t0i - t2i;
    h[t + 2].x = t1r - sgn * t3i; h[t + 2].y = t1i + sgn * t3r;
    h[t + 6].x = t1r + sgn * t3i; h[t + 6].y = t1i - sgn * t3r;
  }
}

// wave shfl reduce + tiny LDS combine (private red buffer per call site).
__device__ __forceinline__ void block_reduce2(float& pr, float& pi,
                                              float* redr, float* redi, int tid) {
  for (int off = 32; off > 0; off >>= 1) {
    pr += __shfl_down(pr, off, 64);
    pi += __shfl_down(pi, off, 64);
  }
  if ((tid & 63) == 0) { redr[tid >> 6] = pr; redi[tid >> 6] = pi; }
  __syncthreads();
  pr = redr[0] + redr[1] + redr[2] + redr[3];
  pi = redi[0] + redi[1] + redi[2] + redi[3];
}

// ---------------- the full row pipeline, ALL global inputs pre-loaded ----------------
// upv[s*8+e] = up value for phase s, element (tid+256e). hxr8/hxi8/pk/bt likewise.
__device__ __forceinline__ void row_pipeline(const float* upv,
                                             const float* hxr8, const float* hxi8,
                                             const int* pk, const float* bt,
                                             float2* sA, float2* sB,
                                             float* redr, float* redi,
                                             int tid, long b, float* out,
                                             long out_size_l, int omode) {
  float2 hreg[8];
  {
    float2 v[8];
#pragma unroll
    for (int e = 0; e < 8; ++e) {
      float sv, cv; __sincosf(upv[e], &sv, &cv);
      v[e].x = cv * hxr8[e] - sv * hxi8[e];
      v[e].y = cv * hxi8[e] + sv * hxr8[e];
    }
    fft8_head(v, sA, tid, -1.f);
  }
  __syncthreads();
  fft8_pass<8>(sA, sB, tid, -1.f);  __syncthreads();
  fft8_pass<64>(sB, sA, tid, -1.f); __syncthreads();
  fft_tail_f(sA, hreg, tid, -1.f);
  float cc[8], ss[8];
  {
    float pr = 0.f, pi = 0.f;
#pragma unroll
    for (int e = 0; e < 8; ++e) {
      float sv, cv; __sincosf(upv[24 + e], &sv, &cv);
      cc[e] = cv; ss[e] = sv;
      pr += cv * hreg[e].x + sv * hreg[e].y;
      pi += cv * hreg[e].y - sv * hreg[e].x;
    }
    block_reduce2(pr, pi, redr, redi, tid);
    const int wb = tid + (tid >> 4);  // PHI(tid); +272e per element
#pragma unroll
    for (int e = 0; e < 8; ++e) {
      sB[wb + 272 * e].x = hreg[e].x - 2.f * (cc[e] * pr - ss[e] * pi);
      sB[wb + 272 * e].y = hreg[e].y - 2.f * (cc[e] * pi + ss[e] * pr);
    }
  }
  __syncthreads();
  {
    const float invN = 1.0f / (float)HID;
    float2 v[8];
#pragma unroll
    for (int e = 0; e < 8; ++e) {
      float sv, cv; __sincosf(upv[8 + e], &sv, &cv);
      int p = pk[e];
      float2 hh = sB[p + (p >> 4)];
      v[e].x = (cv * hh.x - sv * hh.y) * invN;
      v[e].y = (cv * hh.y + sv * hh.x) * invN;
    }
    fft8_head(v, sA, tid, 1.f);
  }
  __syncthreads();
  fft8_pass<8>(sA, sB, tid, 1.f);  __syncthreads();
  fft8_pass<64>(sB, sA, tid, 1.f); __syncthreads();
  fft_tail_f(sA, hreg, tid, 1.f);
  float prj_r, prj_i;
  {
    float pr = 0.f, pi = 0.f;
#pragma unroll
    for (int e = 0; e < 8; ++e) {
      float sv, cv; __sincosf(upv[32 + e], &sv, &cv);
      cc[e] = cv; ss[e] = sv;
      pr += cv * hreg[e].x + sv * hreg[e].y;
      pi += cv * hreg[e].y - sv * hreg[e].x;
    }
    block_reduce2(pr, pi, redr + 4, redi + 4, tid);
    prj_r = pr; prj_i = pi;
  }
#pragma unroll
  for (int e = 0; e < 8; ++e) {
    int k = tid + (e << 8);
    float hr = hreg[e].x - 2.f * (cc[e] * prj_r - ss[e] * prj_i);
    float hi = hreg[e].y - 2.f * (cc[e] * prj_i + ss[e] * prj_r);
    float s3, c3; __sincosf(upv[16 + e], &s3, &c3);
    float zr = c3 * hr - s3 * hi;
    float zi = c3 * hi + s3 * hr;
    float mag = sqrtf(zr * zr + zi * zi);
    float nm = mag + bt[e];
    nm = nm > 0.f ? nm : 0.f;
    float orr, oii;
    if (mag > 0.f) { float sc = nm / mag; orr = zr * sc; oii = zi * sc; }
    else { orr = nm; oii = 0.f; }
    long m = b * HID + k;
    if (omode == 1) {
      const long half = (long)BATCH * HID;
      if (half + m < out_size_l) { out[m] = orr; out[half + m] = oii; }
    } else if (omode == 0) {
      if (2 * m + 1 < out_size_l) {
        float2 o; o.x = orr; o.y = oii;
        *(float2*)(out + 2 * m) = o;
      }
    } else {
      if (m < out_size_l) out[m] = orr;
    }
  }
}

// ---------------- row kernel: 1 row/block, padded f32 LDS, PINNED prefetch ----------
// R6 lesson: read-only loads sink across barriers (compiler chose 64 VGPR, undid
// the prefetch). asm volatile("" : "+v") makes each value opaque: it must be
// materialized here and carried in a VGPR (cannot be re-loaded or rematerialized).
// Budget: 72 pinned + ~40 pipeline peak ~= 112 < 128 allowed by (256,4); LDS
// already caps at 4 blocks/CU so the extra VGPR costs no occupancy.
__global__ __launch_bounds__(256, 4) void urnn_row(const _Float16* __restrict__ up16,
                                                   const float* __restrict__ hxr,
                                                   const float* __restrict__ hxi,
                                                   const float* __restrict__ beta,
                                                   const int* __restrict__ perm,
                                                   float* __restrict__ out,
                                                   int row0, long out_size_l, int omode) {
  __shared__ float2 sA[NPAD], sB[NPAD];
  __shared__ float redr[8], redi[8];

  int tid = threadIdx.x;
  long b = row0 + blockIdx.x;
  const _Float16* uprow = up16 + (size_t)blockIdx.x * FIVEH;

  // ---- one-batch prefetch of everything this row reads ----
  float upv[40], hxr8[8], hxi8[8], bt[8];
  int pk[8];
#pragma unroll
  for (int s = 0; s < 5; ++s)
#pragma unroll
    for (int e = 0; e < 8; ++e)
      upv[s * 8 + e] = (float)uprow[s * HID + tid + (e << 8)];
#pragma unroll
  for (int e = 0; e < 8; ++e) {
    int k = tid + (e << 8);
    hxr8[e] = hxr[(size_t)b * HID + k];
    hxi8[e] = hxi[(size_t)b * HID + k];
    pk[e] = perm[k];
    bt[e] = beta[k];
  }
  // ---- pin: loads must complete here; values live in VGPRs across all barriers ----
#pragma unroll
  for (int i = 0; i < 40; ++i) asm volatile("" : "+v"(upv[i]));
#pragma unroll
  for (int e = 0; e < 8; ++e) {
    asm volatile("" : "+v"(hxr8[e]));
    asm volatile("" : "+v"(hxi8[e]));
    asm volatile("" : "+v"(pk[e]));
    asm volatile("" : "+v"(bt[e]));
  }

  row_pipeline(upv, hxr8, hxi8, pk, bt, sA, sB, redr, redi,
               tid, b, out, out_size_l, omode);
}

// ---------------- ws-free fused fallback (f32-exact per-thread GEMM) ------------------
__global__ __launch_bounds__(256) void urnn_fused(const float* __restrict__ A,
                                                  const float* __restrict__ W,
                                                  const float* __restrict__ bias,
                                                  const float* __restrict__ hxr,
                                                  const float* __restrict__ hxi,
                                                  const float* __restrict__ beta,
                                                  const int* __restrict__ perm,
                                                  float* __restrict__ out,
                                                  long out_size_l, int omode) {
  __shared__ float2 sA[NPAD], sB[NPAD];
  __shared__ float redr[8], redi[8];
  __shared__ float4 xs4[INP / 4];

  int tid = threadIdx.x;
  long b = blockIdx.x;

  if (tid < INP / 4) xs4[tid] = ((const float4*)(A + (size_t)b * INP))[tid];
  __syncthreads();

  float upv[40];
#pragma unroll
  for (int se = 0; se < 40; ++se) {
    int n = ((se >> 3) << 11) + ((se & 7) << 8) + tid;
    upv[se] = bias[n];
  }
  for (int kb = 0; kb < 4; ++kb) {
    float4 xv[8];
#pragma unroll
    for (int j = 0; j < 8; ++j) xv[j] = xs4[kb * 8 + j];
#pragma unroll
    for (int se = 0; se < 40; ++se) {
      int n = ((se >> 3) << 11) + ((se & 7) << 8) + tid;
      const float4* wr = (const float4*)(W + (size_t)n * INP + (kb << 5));
      float a = 0.f;
#pragma unroll
      for (int j = 0; j < 8; ++j) {
        float4 wv = wr[j];
        a += xv[j].x * wv.x + xv[j].y * wv.y + xv[j].z * wv.z + xv[j].w * wv.w;
      }
      upv[se] += a;
    }
  }
  // upv layout is [s*8+e] (n = s*2048 + e*256 + tid), matching row_pipeline.

  float hxr8[8], hxi8[8], bt[8];
  int pk[8];
#pragma unroll
  for (int e = 0; e < 8; ++e) {
    int k = tid + (e << 8);
    hxr8[e] = hxr[(size_t)b * HID + k];
    hxi8[e] = hxi[(size_t)b * HID + k];
    pk[e] = perm[k];
    bt[e] = beta[k];
  }

  row_pipeline(upv, hxr8, hxi8, pk, bt, sA, sB, redr, redi,
               tid, b, out, out_size_l, omode);
}

extern "C" void kernel_launch(void* const* d_in, const int* in_sizes, int n_in,
                              void* d_out, int out_size, void* d_ws, size_t ws_size,
                              hipStream_t stream) {
  const float* input   = (const float*)d_in[0];
  const float* hx_real = (const float*)d_in[1];
  const float* hx_imag = (const float*)d_in[2];
  const float* W       = (const float*)d_in[3];
  const float* bvec    = (const float*)d_in[4];
  const float* beta    = (const float*)d_in[5];
  const int*   perm    = (const int*)d_in[6];

  int omode;
  if (out_size == BATCH * HID) omode = 2;
  else if (out_size == 2 * BATCH * HID) omode = 1;
  else omode = 0;

  const size_t rowbytes = (size_t)FIVEH * sizeof(_Float16);
  long chunk = (long)(ws_size / rowbytes);
  if (chunk > BATCH) chunk = BATCH;
  chunk &= ~127L;

  if (chunk >= 128) {
    _Float16* up16 = (_Float16*)d_ws;
    for (long row0 = 0; row0 < BATCH; row0 += chunk) {
      int rows = (int)((row0 + chunk <= BATCH) ? chunk : (BATCH - row0));
      dim3 g(FIVEH / 128, rows / 128);
      gemm_up<<<g, 256, 0, stream>>>(input, W, bvec, up16, (int)row0, rows);
      urnn_row<<<rows, 256, 0, stream>>>(up16, hx_real, hx_imag, beta, perm,
                                         (float*)d_out, (int)row0, (long)out_size, omode);
    }
  } else {
    urnn_fused<<<BATCH, 256, 0, stream>>>(input, W, bvec, hx_real, hx_imag, beta, perm,
                                          (float*)d_out, (long)out_size, omode);
  }
}